// Round 2
// baseline (1860.282 us; speedup 1.0000x reference)
//
#include <hip/hip_runtime.h>
#include <math.h>

#define HID   64
#define OUTC  40
#define CAP   64   // max in-degree bucket capacity (Poisson(16): P(overflow) ~ 1e-13)

// ---------------- degree histogram ----------------
__global__ void deg_kernel(const int* __restrict__ dst, int* __restrict__ cnt, int E) {
    int e = blockIdx.x * blockDim.x + threadIdx.x;
    if (e < E) atomicAdd(&cnt[dst[e]], 1);
}

// dinv = rsqrt(deg+1); reset cnt for reuse as fill cursor
__global__ void dinv_kernel(int* __restrict__ cnt, float* __restrict__ dinv, int N) {
    int i = blockIdx.x * blockDim.x + threadIdx.x;
    if (i < N) {
        dinv[i] = rsqrtf((float)cnt[i] + 1.0f);
        cnt[i] = 0;
    }
}

// bucket fill: recs[dst][slot] = (src, enorm)
__global__ void fill_kernel(const int* __restrict__ src, const int* __restrict__ dst,
                            const float* __restrict__ dinv, int* __restrict__ cnt,
                            int2* __restrict__ recs, int E) {
    int e = blockIdx.x * blockDim.x + threadIdx.x;
    if (e < E) {
        int s = src[e], d = dst[e];
        float en = dinv[s] * dinv[d];
        int pos = atomicAdd(&cnt[d], 1);
        if (pos < CAP) recs[(size_t)d * CAP + pos] = make_int2(s, __float_as_int(en));
    }
}

// ---------------- dense transform: out[N,64] = X[N,CIN] @ W[CIN,64] ----------------
// One wave computes 4 rows: each W vector-load is reused for 4 FMAs.
template<int CIN>
__global__ void gemm_kernel(const float* __restrict__ X, const float* __restrict__ W,
                            float* __restrict__ out, int N) {
    int lane = threadIdx.x & 63;
    int wv   = blockIdx.x * (blockDim.x >> 6) + (threadIdx.x >> 6);
    int row0 = wv << 2;
    if (row0 >= N) return;

    float xv[4][CIN / 64];
    #pragma unroll
    for (int r = 0; r < 4; r++) {
        int rr = row0 + r; if (rr > N - 1) rr = N - 1;  // clamp loads, mask stores
        const float* xr = X + (size_t)rr * CIN;
        #pragma unroll
        for (int j = 0; j < CIN / 64; j++) xv[r][j] = xr[j * 64 + lane];
    }
    float acc[4] = {0.f, 0.f, 0.f, 0.f};
    #pragma unroll
    for (int j = 0; j < CIN / 64; j++) {
        #pragma unroll
        for (int k = 0; k < 64; k++) {
            float w = W[(size_t)(j * 64 + k) * HID + lane];
            #pragma unroll
            for (int r = 0; r < 4; r++)
                acc[r] = fmaf(__shfl(xv[r][j], k), w, acc[r]);
        }
    }
    #pragma unroll
    for (int r = 0; r < 4; r++)
        if (row0 + r < N) out[(size_t)(row0 + r) * HID + lane] = acc[r];
}

// ---------------- gather-aggregate + self-loop + bias (+ LN + ReLU) ----------------
template<bool LN>
__global__ void conv_kernel(const float* __restrict__ hw, const int2* __restrict__ recs,
                            const int* __restrict__ cnt, const float* __restrict__ dinv,
                            const float* __restrict__ b, const float* __restrict__ g,
                            const float* __restrict__ be, float* __restrict__ out, int N) {
    int lane = threadIdx.x & 63;
    int row  = (blockIdx.x << 2) + (threadIdx.x >> 6);
    if (row >= N) return;

    int c = cnt[row];
    if (c > CAP) c = CAP;

    // lane-parallel preload of this node's edge records, broadcast via shfl
    int2 myrec = make_int2(0, 0);
    if (lane < c) myrec = recs[(size_t)row * CAP + lane];

    float acc = 0.f;
    for (int k = 0; k < c; k++) {
        int   s  = __shfl(myrec.x, k);
        float en = __shfl(__int_as_float(myrec.y), k);
        acc = fmaf(en, hw[(size_t)s * HID + lane], acc);
    }
    float di = dinv[row];
    acc = fmaf(di * di, hw[(size_t)row * HID + lane], acc) + b[lane];

    if (LN) {
        float s = acc;
        #pragma unroll
        for (int o = 32; o; o >>= 1) s += __shfl_xor(s, o);
        float mu = s * (1.f / 64.f);
        float d0 = acc - mu;
        float v  = d0 * d0;
        #pragma unroll
        for (int o = 32; o; o >>= 1) v += __shfl_xor(v, o);
        v *= (1.f / 64.f);
        acc = d0 * rsqrtf(v + 1e-5f) * g[lane] + be[lane];
        acc = fmaxf(acc, 0.f);
    }
    out[(size_t)row * HID + lane] = acc;
}

// ---------------- MLP (64->64 relu ->40) + softmax ----------------
// One wave per 64-node tile; lane = node. h tile LDS-transposed (pad 65,
// conflict-free column reads). Weights are wave-uniform -> scalar loads
// (s_load, L1-cached). acc/o live in registers with static indexing only.
__global__ __launch_bounds__(64) void mlp_kernel(const float* __restrict__ h,
                           const float* __restrict__ M1, const float* __restrict__ mb1,
                           const float* __restrict__ M2, const float* __restrict__ mb2,
                           float* __restrict__ out, int N) {
    __shared__ float tl[64 * 65];
    int lane = threadIdx.x;
    int base = blockIdx.x << 6;
    if (base >= N) return;
    int nvalid = N - base; if (nvalid > 64) nvalid = 64;

    // stage h tile [nvalid x 64] into LDS rows with pad 65
    for (int i = lane; i < nvalid * 16; i += 64) {
        float4 v = ((const float4*)(h + ((size_t)base << 6)))[i];
        int a = (i >> 4) * 65 + ((i & 15) << 2);
        tl[a] = v.x; tl[a + 1] = v.y; tl[a + 2] = v.z; tl[a + 3] = v.w;
    }
    __syncthreads();

    // layer M1 + bias: acc[j] = sum_k h[lane][k] * M1[k][j]
    float acc[64];
    #pragma unroll
    for (int j = 0; j < 64; j++) acc[j] = mb1[j];
    #pragma unroll 2
    for (int k = 0; k < 64; k++) {
        float hk = tl[lane * 65 + k];          // bank = (lane+k)%32 -> 2-way, free
        const float* wr = M1 + (k << 6);       // wave-uniform -> s_load
        #pragma unroll
        for (int j = 0; j < 64; j++) acc[j] = fmaf(hk, wr[j], acc[j]);
    }

    // relu + layer M2 + bias (fully unrolled: acc[k] must be static-indexed)
    float o[40];
    #pragma unroll
    for (int j = 0; j < 40; j++) o[j] = mb2[j];
    #pragma unroll
    for (int k = 0; k < 64; k++) {
        float hk = fmaxf(acc[k], 0.f);
        const float* wr = M2 + k * 40;         // wave-uniform -> s_load
        #pragma unroll
        for (int j = 0; j < 40; j++) o[j] = fmaf(hk, wr[j], o[j]);
    }

    // softmax per lane, in registers
    float mx = o[0];
    #pragma unroll
    for (int j = 1; j < 40; j++) mx = fmaxf(mx, o[j]);
    float sum = 0.f;
    #pragma unroll
    for (int j = 0; j < 40; j++) { o[j] = __expf(o[j] - mx); sum += o[j]; }
    float inv = 1.f / sum;

    // transpose through LDS (pad 41 -> conflict-free writes), coalesced store
    __syncthreads();  // all lanes done reading h tile before overwrite
    #pragma unroll
    for (int j = 0; j < 40; j++) tl[lane * 41 + j] = o[j] * inv;
    __syncthreads();
    for (int i = lane; i < nvalid * 40; i += 64)
        out[(size_t)base * 40 + i] = tl[(i / 40) * 41 + (i % 40)];
}

extern "C" void kernel_launch(void* const* d_in, const int* in_sizes, int n_in,
                              void* d_out, int out_size, void* d_ws, size_t ws_size,
                              hipStream_t stream) {
    const float* x   = (const float*)d_in[0];
    const int*   ei  = (const int*)  d_in[1];
    const float* W1  = (const float*)d_in[2];
    const float* b1  = (const float*)d_in[3];
    const float* W2  = (const float*)d_in[4];
    const float* b2  = (const float*)d_in[5];
    const float* W3  = (const float*)d_in[6];
    const float* b3  = (const float*)d_in[7];
    const float* g1  = (const float*)d_in[8];
    const float* be1 = (const float*)d_in[9];
    const float* g2  = (const float*)d_in[10];
    const float* be2 = (const float*)d_in[11];
    const float* M1  = (const float*)d_in[12];
    const float* mb1 = (const float*)d_in[13];
    const float* M2  = (const float*)d_in[14];
    const float* mb2 = (const float*)d_in[15];

    const int IN_C = 128;
    int N = in_sizes[0] / IN_C;
    int E = in_sizes[1] / 2;
    const int* src = ei;
    const int* dst = ei + E;

    // workspace carve-up
    char* ws = (char*)d_ws;
    size_t off = 0;
    auto carve = [&](size_t bytes) -> void* {
        void* p = ws + off;
        off = (off + bytes + 255) & ~(size_t)255;
        return p;
    };
    int*   cnt  = (int*)  carve((size_t)N * sizeof(int));
    float* dinv = (float*)carve((size_t)N * sizeof(float));
    int2*  recs = (int2*) carve((size_t)N * CAP * sizeof(int2));
    float* HW   = (float*)carve((size_t)N * HID * sizeof(float));
    float* H    = (float*)carve((size_t)N * HID * sizeof(float));

    hipMemsetAsync(cnt, 0, (size_t)N * sizeof(int), stream);

    int eb = (E + 255) / 256;
    int nb = (N + 255) / 256;
    int rb = (N + 3) / 4;            // conv: one wave per node, 4 waves/block
    int gb = ((N + 3) / 4 + 3) / 4;  // gemm: 4 rows per wave, 4 waves/block
    int mb = (N + 63) / 64;          // mlp: one 64-thread block per 64-node tile

    deg_kernel <<<eb, 256, 0, stream>>>(dst, cnt, E);
    dinv_kernel<<<nb, 256, 0, stream>>>(cnt, dinv, N);
    fill_kernel<<<eb, 256, 0, stream>>>(src, dst, dinv, cnt, recs, E);

    // layer 1
    gemm_kernel<128><<<gb, 256, 0, stream>>>(x, W1, HW, N);
    conv_kernel<true><<<rb, 256, 0, stream>>>(HW, recs, cnt, dinv, b1, g1, be1, H, N);
    // layer 2
    gemm_kernel<64><<<gb, 256, 0, stream>>>(H, W2, HW, N);
    conv_kernel<true><<<rb, 256, 0, stream>>>(HW, recs, cnt, dinv, b2, g2, be2, H, N);
    // layer 3 (no LN/ReLU)
    gemm_kernel<64><<<gb, 256, 0, stream>>>(H, W3, HW, N);
    conv_kernel<false><<<rb, 256, 0, stream>>>(HW, recs, cnt, dinv, b3, nullptr, nullptr, H, N);

    // MLP + softmax
    mlp_kernel<<<mb, 64, 0, stream>>>(H, M1, mb1, M2, mb2, (float*)d_out, N);
}

// Round 3
// 419.651 us; speedup vs baseline: 4.4329x; 4.4329x over previous
//
#include <hip/hip_runtime.h>
#include <math.h>

#define HID   64
#define OUTC  40
#define CAP   64   // max in-degree bucket capacity (Poisson(16): P(overflow) ~ 1e-13)

// ---------------- degree histogram ----------------
__global__ void deg_kernel(const int* __restrict__ dst, int* __restrict__ cnt, int E) {
    int e = blockIdx.x * blockDim.x + threadIdx.x;
    if (e < E) atomicAdd(&cnt[dst[e]], 1);
}

// dinv = rsqrt(deg+1); reset cnt for reuse as fill cursor
__global__ void dinv_kernel(int* __restrict__ cnt, float* __restrict__ dinv, int N) {
    int i = blockIdx.x * blockDim.x + threadIdx.x;
    if (i < N) {
        dinv[i] = rsqrtf((float)cnt[i] + 1.0f);
        cnt[i] = 0;
    }
}

// bucket fill: recs[dst][slot] = (src, enorm)
__global__ void fill_kernel(const int* __restrict__ src, const int* __restrict__ dst,
                            const float* __restrict__ dinv, int* __restrict__ cnt,
                            int2* __restrict__ recs, int E) {
    int e = blockIdx.x * blockDim.x + threadIdx.x;
    if (e < E) {
        int s = src[e], d = dst[e];
        float en = dinv[s] * dinv[d];
        int pos = atomicAdd(&cnt[d], 1);
        if (pos < CAP) recs[(size_t)d * CAP + pos] = make_int2(s, __float_as_int(en));
    }
}

// ---------------- dense transform: out[N,64] = X[N,CIN] @ W[CIN,64] ----------------
// mlp-proven structure: lane = node, 64-node tile. X tile staged in LDS
// ([64][CIN+1] pad -> 2-way bank access, free). W rows are wave-uniform ->
// scalar loads through K$. acc[64] statically indexed in registers (no spill).
template<int CIN>
__global__ __launch_bounds__(64) void xform_kernel(const float* __restrict__ X,
                                                   const float* __restrict__ W,
                                                   float* __restrict__ out, int N) {
    constexpr int PAD = CIN + 1;
    __shared__ float tl[64 * PAD];   // CIN>=64 so this also fits the 64*65 output transpose
    int lane = threadIdx.x;
    int base = blockIdx.x << 6;
    if (base >= N) return;
    int nvalid = N - base; if (nvalid > 64) nvalid = 64;

    // stage X tile [nvalid x CIN], float4-coalesced
    for (int i = lane; i < nvalid * (CIN / 4); i += 64) {
        float4 v = ((const float4*)(X + (size_t)base * CIN))[i];
        int a = (i / (CIN / 4)) * PAD + (i % (CIN / 4)) * 4;
        tl[a] = v.x; tl[a + 1] = v.y; tl[a + 2] = v.z; tl[a + 3] = v.w;
    }
    __syncthreads();

    float acc[64];
    #pragma unroll
    for (int j = 0; j < 64; j++) acc[j] = 0.f;
    #pragma unroll 2
    for (int k = 0; k < CIN; k++) {
        float xk = tl[lane * PAD + k];       // bank (lane+k)%32 -> 2-way, free
        const float* wr = W + (k << 6);      // wave-uniform -> s_load
        #pragma unroll
        for (int j = 0; j < 64; j++) acc[j] = fmaf(xk, wr[j], acc[j]);
    }

    // transpose through LDS for coalesced float4 stores
    __syncthreads();
    #pragma unroll
    for (int j = 0; j < 64; j++) tl[lane * 65 + j] = acc[j];
    __syncthreads();
    for (int i = lane; i < nvalid * 16; i += 64) {
        int a = (i >> 4) * 65 + ((i & 15) << 2);
        float4 v = make_float4(tl[a], tl[a + 1], tl[a + 2], tl[a + 3]);
        ((float4*)(out + ((size_t)base << 6)))[i] = v;
    }
}

// ---------------- gather-aggregate + self-loop + bias (+ LN + ReLU) ----------------
template<bool LN>
__global__ void conv_kernel(const float* __restrict__ hw, const int2* __restrict__ recs,
                            const int* __restrict__ cnt, const float* __restrict__ dinv,
                            const float* __restrict__ b, const float* __restrict__ g,
                            const float* __restrict__ be, float* __restrict__ out, int N) {
    int lane = threadIdx.x & 63;
    int row  = (blockIdx.x << 2) + (threadIdx.x >> 6);
    if (row >= N) return;

    int c = cnt[row];
    if (c > CAP) c = CAP;

    // lane-parallel preload of this node's edge records, broadcast via shfl
    int2 myrec = make_int2(0, 0);
    if (lane < c) myrec = recs[(size_t)row * CAP + lane];

    float acc = 0.f;
    for (int k = 0; k < c; k++) {
        int   s  = __shfl(myrec.x, k);
        float en = __shfl(__int_as_float(myrec.y), k);
        acc = fmaf(en, hw[(size_t)s * HID + lane], acc);
    }
    float di = dinv[row];
    acc = fmaf(di * di, hw[(size_t)row * HID + lane], acc) + b[lane];

    if (LN) {
        float s = acc;
        #pragma unroll
        for (int o = 32; o; o >>= 1) s += __shfl_xor(s, o);
        float mu = s * (1.f / 64.f);
        float d0 = acc - mu;
        float v  = d0 * d0;
        #pragma unroll
        for (int o = 32; o; o >>= 1) v += __shfl_xor(v, o);
        v *= (1.f / 64.f);
        acc = d0 * rsqrtf(v + 1e-5f) * g[lane] + be[lane];
        acc = fmaxf(acc, 0.f);
    }
    out[(size_t)row * HID + lane] = acc;
}

// ---------------- MLP (64->64 relu ->40) + softmax ----------------
__global__ __launch_bounds__(64) void mlp_kernel(const float* __restrict__ h,
                           const float* __restrict__ M1, const float* __restrict__ mb1,
                           const float* __restrict__ M2, const float* __restrict__ mb2,
                           float* __restrict__ out, int N) {
    __shared__ float tl[64 * 65];
    int lane = threadIdx.x;
    int base = blockIdx.x << 6;
    if (base >= N) return;
    int nvalid = N - base; if (nvalid > 64) nvalid = 64;

    // stage h tile [nvalid x 64] into LDS rows with pad 65
    for (int i = lane; i < nvalid * 16; i += 64) {
        float4 v = ((const float4*)(h + ((size_t)base << 6)))[i];
        int a = (i >> 4) * 65 + ((i & 15) << 2);
        tl[a] = v.x; tl[a + 1] = v.y; tl[a + 2] = v.z; tl[a + 3] = v.w;
    }
    __syncthreads();

    // layer M1 + bias: acc[j] = sum_k h[lane][k] * M1[k][j]
    float acc[64];
    #pragma unroll
    for (int j = 0; j < 64; j++) acc[j] = mb1[j];
    #pragma unroll 2
    for (int k = 0; k < 64; k++) {
        float hk = tl[lane * 65 + k];          // 2-way bank access, free
        const float* wr = M1 + (k << 6);       // wave-uniform -> s_load
        #pragma unroll
        for (int j = 0; j < 64; j++) acc[j] = fmaf(hk, wr[j], acc[j]);
    }

    // relu + layer M2 + bias (fully unrolled: acc[k] static-indexed)
    float o[40];
    #pragma unroll
    for (int j = 0; j < 40; j++) o[j] = mb2[j];
    #pragma unroll
    for (int k = 0; k < 64; k++) {
        float hk = fmaxf(acc[k], 0.f);
        const float* wr = M2 + k * 40;         // wave-uniform -> s_load
        #pragma unroll
        for (int j = 0; j < 40; j++) o[j] = fmaf(hk, wr[j], o[j]);
    }

    // softmax per lane, in registers
    float mx = o[0];
    #pragma unroll
    for (int j = 1; j < 40; j++) mx = fmaxf(mx, o[j]);
    float sum = 0.f;
    #pragma unroll
    for (int j = 0; j < 40; j++) { o[j] = __expf(o[j] - mx); sum += o[j]; }
    float inv = 1.f / sum;

    // transpose through LDS (pad 41), coalesced store
    __syncthreads();
    #pragma unroll
    for (int j = 0; j < 40; j++) tl[lane * 41 + j] = o[j] * inv;
    __syncthreads();
    for (int i = lane; i < nvalid * 40; i += 64)
        out[(size_t)base * 40 + i] = tl[(i / 40) * 41 + (i % 40)];
}

extern "C" void kernel_launch(void* const* d_in, const int* in_sizes, int n_in,
                              void* d_out, int out_size, void* d_ws, size_t ws_size,
                              hipStream_t stream) {
    const float* x   = (const float*)d_in[0];
    const int*   ei  = (const int*)  d_in[1];
    const float* W1  = (const float*)d_in[2];
    const float* b1  = (const float*)d_in[3];
    const float* W2  = (const float*)d_in[4];
    const float* b2  = (const float*)d_in[5];
    const float* W3  = (const float*)d_in[6];
    const float* b3  = (const float*)d_in[7];
    const float* g1  = (const float*)d_in[8];
    const float* be1 = (const float*)d_in[9];
    const float* g2  = (const float*)d_in[10];
    const float* be2 = (const float*)d_in[11];
    const float* M1  = (const float*)d_in[12];
    const float* mb1 = (const float*)d_in[13];
    const float* M2  = (const float*)d_in[14];
    const float* mb2 = (const float*)d_in[15];

    const int IN_C = 128;
    int N = in_sizes[0] / IN_C;
    int E = in_sizes[1] / 2;
    const int* src = ei;
    const int* dst = ei + E;

    // workspace carve-up
    char* ws = (char*)d_ws;
    size_t off = 0;
    auto carve = [&](size_t bytes) -> void* {
        void* p = ws + off;
        off = (off + bytes + 255) & ~(size_t)255;
        return p;
    };
    int*   cnt  = (int*)  carve((size_t)N * sizeof(int));
    float* dinv = (float*)carve((size_t)N * sizeof(float));
    int2*  recs = (int2*) carve((size_t)N * CAP * sizeof(int2));
    float* HW   = (float*)carve((size_t)N * HID * sizeof(float));
    float* H    = (float*)carve((size_t)N * HID * sizeof(float));

    hipMemsetAsync(cnt, 0, (size_t)N * sizeof(int), stream);

    int eb = (E + 255) / 256;
    int nb = (N + 255) / 256;
    int rb = (N + 3) / 4;    // conv: one wave per node, 4 waves/block
    int tb = (N + 63) / 64;  // xform/mlp: one 64-thread block per 64-node tile

    deg_kernel <<<eb, 256, 0, stream>>>(dst, cnt, E);
    dinv_kernel<<<nb, 256, 0, stream>>>(cnt, dinv, N);
    fill_kernel<<<eb, 256, 0, stream>>>(src, dst, dinv, cnt, recs, E);

    // layer 1
    xform_kernel<128><<<tb, 64, 0, stream>>>(x, W1, HW, N);
    conv_kernel<true><<<rb, 256, 0, stream>>>(HW, recs, cnt, dinv, b1, g1, be1, H, N);
    // layer 2
    xform_kernel<64><<<tb, 64, 0, stream>>>(H, W2, HW, N);
    conv_kernel<true><<<rb, 256, 0, stream>>>(HW, recs, cnt, dinv, b2, g2, be2, H, N);
    // layer 3 (no LN/ReLU)
    xform_kernel<64><<<tb, 64, 0, stream>>>(H, W3, HW, N);
    conv_kernel<false><<<rb, 256, 0, stream>>>(HW, recs, cnt, dinv, b3, nullptr, nullptr, H, N);

    // MLP + softmax
    mlp_kernel<<<tb, 64, 0, stream>>>(H, M1, mb1, M2, mb2, (float*)d_out, N);
}

// Round 4
// 407.548 us; speedup vs baseline: 4.5646x; 1.0297x over previous
//
#include <hip/hip_runtime.h>
#include <math.h>

#define HID   64
#define OUTC  40
#define CAP   64   // max in-degree bucket capacity (Poisson(16): P(overflow) ~ 1e-13)

// ---------------- degree histogram ----------------
__global__ void deg_kernel(const int* __restrict__ dst, int* __restrict__ cnt, int E) {
    int e = blockIdx.x * blockDim.x + threadIdx.x;
    if (e < E) atomicAdd(&cnt[dst[e]], 1);
}

// dinv = rsqrt(deg+1); reset cnt for reuse as fill cursor
__global__ void dinv_kernel(int* __restrict__ cnt, float* __restrict__ dinv, int N) {
    int i = blockIdx.x * blockDim.x + threadIdx.x;
    if (i < N) {
        dinv[i] = rsqrtf((float)cnt[i] + 1.0f);
        cnt[i] = 0;
    }
}

// bucket fill: recs[dst][slot] = (src, enorm)
__global__ void fill_kernel(const int* __restrict__ src, const int* __restrict__ dst,
                            const float* __restrict__ dinv, int* __restrict__ cnt,
                            int2* __restrict__ recs, int E) {
    int e = blockIdx.x * blockDim.x + threadIdx.x;
    if (e < E) {
        int s = src[e], d = dst[e];
        float en = dinv[s] * dinv[d];
        int pos = atomicAdd(&cnt[d], 1);
        if (pos < CAP) recs[(size_t)d * CAP + pos] = make_int2(s, __float_as_int(en));
    }
}

// ---------------- dense transform: out[N,64] = X[N,CIN] @ W[CIN,64] ----------------
// lane = output column j. W[:,lane] preloaded into VGPRs (one coalesced load
// per k, L2-hot, shared by all waves). X tile staged LINEAR in LDS; rows read
// as wave-uniform ds_read_b128 broadcasts (no bank conflicts by definition).
// 4 accumulator chains break the serial FMA dependency.
template<int CIN>
__global__ __launch_bounds__(64) void xform_kernel(const float* __restrict__ X,
                                                   const float* __restrict__ W,
                                                   float* __restrict__ out, int N) {
    __shared__ float tl[64 * CIN];
    int lane = threadIdx.x;
    int base = blockIdx.x << 6;
    if (base >= N) return;
    int nvalid = N - base; if (nvalid > 64) nvalid = 64;

    float wreg[CIN];
    #pragma unroll
    for (int k = 0; k < CIN; k++) wreg[k] = W[(k << 6) + lane];

    const float4* xs = (const float4*)(X + (size_t)base * CIN);
    float4* tl4 = (float4*)tl;
    for (int i = lane; i < nvalid * (CIN / 4); i += 64) tl4[i] = xs[i];
    __syncthreads();

    float* outp = out + ((size_t)base << 6) + lane;
    if (nvalid == 64) {
        #pragma unroll 2
        for (int n = 0; n < 64; n++) {
            float a0 = 0.f, a1 = 0.f, a2 = 0.f, a3 = 0.f;
            #pragma unroll
            for (int q = 0; q < CIN / 4; q++) {
                float4 xq = tl4[n * (CIN / 4) + q];   // wave-uniform broadcast
                a0 = fmaf(xq.x, wreg[4 * q + 0], a0);
                a1 = fmaf(xq.y, wreg[4 * q + 1], a1);
                a2 = fmaf(xq.z, wreg[4 * q + 2], a2);
                a3 = fmaf(xq.w, wreg[4 * q + 3], a3);
            }
            outp[(size_t)n << 6] = (a0 + a1) + (a2 + a3);
        }
    } else {
        for (int n = 0; n < nvalid; n++) {
            float a0 = 0.f, a1 = 0.f, a2 = 0.f, a3 = 0.f;
            #pragma unroll
            for (int q = 0; q < CIN / 4; q++) {
                float4 xq = tl4[n * (CIN / 4) + q];
                a0 = fmaf(xq.x, wreg[4 * q + 0], a0);
                a1 = fmaf(xq.y, wreg[4 * q + 1], a1);
                a2 = fmaf(xq.z, wreg[4 * q + 2], a2);
                a3 = fmaf(xq.w, wreg[4 * q + 3], a3);
            }
            outp[(size_t)n << 6] = (a0 + a1) + (a2 + a3);
        }
    }
}

// ---------------- gather-aggregate + self-loop + bias (+ LN + ReLU) ----------------
// 4-deep unrolled edge loop: 4 independent loads in flight per wave.
template<bool LN>
__global__ void conv_kernel(const float* __restrict__ hw, const int2* __restrict__ recs,
                            const int* __restrict__ cnt, const float* __restrict__ dinv,
                            const float* __restrict__ b, const float* __restrict__ g,
                            const float* __restrict__ be, float* __restrict__ out, int N) {
    int lane = threadIdx.x & 63;
    int row  = (blockIdx.x << 2) + (threadIdx.x >> 6);
    if (row >= N) return;

    int c = cnt[row];
    if (c > CAP) c = CAP;

    int2 myrec = make_int2(0, 0);
    if (lane < c) myrec = recs[(size_t)row * CAP + lane];

    float di    = dinv[row];
    float selfv = hw[((size_t)row << 6) + lane];   // issue early

    float a0 = 0.f, a1 = 0.f, a2 = 0.f, a3 = 0.f;
    int k = 0;
    for (; k + 4 <= c; k += 4) {
        int   s0 = __shfl(myrec.x, k + 0), s1 = __shfl(myrec.x, k + 1),
              s2 = __shfl(myrec.x, k + 2), s3 = __shfl(myrec.x, k + 3);
        float e0 = __shfl(__int_as_float(myrec.y), k + 0),
              e1 = __shfl(__int_as_float(myrec.y), k + 1),
              e2 = __shfl(__int_as_float(myrec.y), k + 2),
              e3 = __shfl(__int_as_float(myrec.y), k + 3);
        float v0 = hw[((size_t)s0 << 6) + lane];
        float v1 = hw[((size_t)s1 << 6) + lane];
        float v2 = hw[((size_t)s2 << 6) + lane];
        float v3 = hw[((size_t)s3 << 6) + lane];
        a0 = fmaf(e0, v0, a0); a1 = fmaf(e1, v1, a1);
        a2 = fmaf(e2, v2, a2); a3 = fmaf(e3, v3, a3);
    }
    for (; k < c; k++) {
        int   s  = __shfl(myrec.x, k);
        float en = __shfl(__int_as_float(myrec.y), k);
        a0 = fmaf(en, hw[((size_t)s << 6) + lane], a0);
    }
    float acc = (a0 + a1) + (a2 + a3);
    acc = fmaf(di * di, selfv, acc) + b[lane];

    if (LN) {
        float s = acc;
        #pragma unroll
        for (int o = 32; o; o >>= 1) s += __shfl_xor(s, o);
        float mu = s * (1.f / 64.f);
        float d0 = acc - mu;
        float v  = d0 * d0;
        #pragma unroll
        for (int o = 32; o; o >>= 1) v += __shfl_xor(v, o);
        v *= (1.f / 64.f);
        acc = d0 * rsqrtf(v + 1e-5f) * g[lane] + be[lane];
        acc = fmaxf(acc, 0.f);
    }
    out[((size_t)row << 6) + lane] = acc;
}

// ---------------- MLP (64->64 relu ->40) + softmax ----------------
// lane = output column. M1/M2 columns in VGPRs; h tile + h2 broadcast via LDS.
__global__ __launch_bounds__(64) void mlp_kernel(const float* __restrict__ h,
                           const float* __restrict__ M1, const float* __restrict__ mb1,
                           const float* __restrict__ M2, const float* __restrict__ mb2,
                           float* __restrict__ out, int N) {
    __shared__ float tl[64 * 64];
    __shared__ float h2buf[64];
    int lane = threadIdx.x;
    int base = blockIdx.x << 6;
    if (base >= N) return;
    int nvalid = N - base; if (nvalid > 64) nvalid = 64;

    float m1reg[64], m2reg[64];
    #pragma unroll
    for (int k = 0; k < 64; k++) m1reg[k] = M1[(k << 6) + lane];
    #pragma unroll
    for (int k = 0; k < 64; k++) m2reg[k] = (lane < OUTC) ? M2[k * OUTC + lane] : 0.f;
    float b1v = mb1[lane];
    float b2v = (lane < OUTC) ? mb2[lane] : 0.f;

    const float4* hs = (const float4*)(h + ((size_t)base << 6));
    float4* tl4 = (float4*)tl;
    for (int i = lane; i < nvalid * 16; i += 64) tl4[i] = hs[i];
    __syncthreads();

    float4* h2b4 = (float4*)h2buf;
    for (int n = 0; n < nvalid; n++) {
        // M1 matvec: 16 wave-uniform b128 broadcasts x register column
        float a0 = 0.f, a1 = 0.f, a2 = 0.f, a3 = 0.f;
        #pragma unroll
        for (int q = 0; q < 16; q++) {
            float4 xq = tl4[n * 16 + q];
            a0 = fmaf(xq.x, m1reg[4 * q + 0], a0);
            a1 = fmaf(xq.y, m1reg[4 * q + 1], a1);
            a2 = fmaf(xq.z, m1reg[4 * q + 2], a2);
            a3 = fmaf(xq.w, m1reg[4 * q + 3], a3);
        }
        float h2 = fmaxf((a0 + a1) + (a2 + a3) + b1v, 0.f);

        __syncthreads();           // previous iteration's h2buf reads complete
        h2buf[lane] = h2;
        __syncthreads();

        a0 = a1 = a2 = a3 = 0.f;
        #pragma unroll
        for (int q = 0; q < 16; q++) {
            float4 xq = h2b4[q];
            a0 = fmaf(xq.x, m2reg[4 * q + 0], a0);
            a1 = fmaf(xq.y, m2reg[4 * q + 1], a1);
            a2 = fmaf(xq.z, m2reg[4 * q + 2], a2);
            a3 = fmaf(xq.w, m2reg[4 * q + 3], a3);
        }
        float o = (a0 + a1) + (a2 + a3) + b2v;

        float logit = (lane < OUTC) ? o : -INFINITY;
        float mx = logit;
        #pragma unroll
        for (int s = 32; s; s >>= 1) mx = fmaxf(mx, __shfl_xor(mx, s));
        float e = (lane < OUTC) ? __expf(logit - mx) : 0.f;
        float sum = e;
        #pragma unroll
        for (int s = 32; s; s >>= 1) sum += __shfl_xor(sum, s);
        if (lane < OUTC) out[(size_t)(base + n) * OUTC + lane] = e / sum;
    }
}

extern "C" void kernel_launch(void* const* d_in, const int* in_sizes, int n_in,
                              void* d_out, int out_size, void* d_ws, size_t ws_size,
                              hipStream_t stream) {
    const float* x   = (const float*)d_in[0];
    const int*   ei  = (const int*)  d_in[1];
    const float* W1  = (const float*)d_in[2];
    const float* b1  = (const float*)d_in[3];
    const float* W2  = (const float*)d_in[4];
    const float* b2  = (const float*)d_in[5];
    const float* W3  = (const float*)d_in[6];
    const float* b3  = (const float*)d_in[7];
    const float* g1  = (const float*)d_in[8];
    const float* be1 = (const float*)d_in[9];
    const float* g2  = (const float*)d_in[10];
    const float* be2 = (const float*)d_in[11];
    const float* M1  = (const float*)d_in[12];
    const float* mb1 = (const float*)d_in[13];
    const float* M2  = (const float*)d_in[14];
    const float* mb2 = (const float*)d_in[15];

    const int IN_C = 128;
    int N = in_sizes[0] / IN_C;
    int E = in_sizes[1] / 2;
    const int* src = ei;
    const int* dst = ei + E;

    // workspace carve-up
    char* ws = (char*)d_ws;
    size_t off = 0;
    auto carve = [&](size_t bytes) -> void* {
        void* p = ws + off;
        off = (off + bytes + 255) & ~(size_t)255;
        return p;
    };
    int*   cnt  = (int*)  carve((size_t)N * sizeof(int));
    float* dinv = (float*)carve((size_t)N * sizeof(float));
    int2*  recs = (int2*) carve((size_t)N * CAP * sizeof(int2));
    float* HW   = (float*)carve((size_t)N * HID * sizeof(float));
    float* H    = (float*)carve((size_t)N * HID * sizeof(float));

    hipMemsetAsync(cnt, 0, (size_t)N * sizeof(int), stream);

    int eb = (E + 255) / 256;
    int nb = (N + 255) / 256;
    int rb = (N + 3) / 4;    // conv: one wave per node, 4 waves/block
    int tb = (N + 63) / 64;  // xform/mlp: one 64-thread block per 64-node tile

    deg_kernel <<<eb, 256, 0, stream>>>(dst, cnt, E);
    dinv_kernel<<<nb, 256, 0, stream>>>(cnt, dinv, N);
    fill_kernel<<<eb, 256, 0, stream>>>(src, dst, dinv, cnt, recs, E);

    // layer 1
    xform_kernel<128><<<tb, 64, 0, stream>>>(x, W1, HW, N);
    conv_kernel<true><<<rb, 256, 0, stream>>>(HW, recs, cnt, dinv, b1, g1, be1, H, N);
    // layer 2
    xform_kernel<64><<<tb, 64, 0, stream>>>(H, W2, HW, N);
    conv_kernel<true><<<rb, 256, 0, stream>>>(HW, recs, cnt, dinv, b2, g2, be2, H, N);
    // layer 3 (no LN/ReLU)
    xform_kernel<64><<<tb, 64, 0, stream>>>(H, W3, HW, N);
    conv_kernel<false><<<rb, 256, 0, stream>>>(HW, recs, cnt, dinv, b3, nullptr, nullptr, H, N);

    // MLP + softmax
    mlp_kernel<<<tb, 64, 0, stream>>>(H, M1, mb1, M2, mb2, (float*)d_out, N);
}